// Round 2
// baseline (4300.086 us; speedup 1.0000x reference)
//
#include <hip/hip_runtime.h>

// GraphEncoder: 3x (GCNConv -> [ReLU -> LayerNorm]) on N=100000 nodes, E=1.6M edges.
// All fp32. Layer dims: 128->64, 64->64, 64->64.

constexpr float LN_EPS = 1e-5f;

// ---------------- degree ----------------
__global__ void deg_kernel(const int* __restrict__ dst, int E, float* __restrict__ deg) {
    int i = blockIdx.x * blockDim.x + threadIdx.x;
    int stride = gridDim.x * blockDim.x;
    for (; i < E; i += stride) {
        atomicAdd(&deg[dst[i]], 1.0f);
    }
}

__global__ void dinv_kernel(float* __restrict__ deg, int n) {
    int i = blockIdx.x * blockDim.x + threadIdx.x;
    if (i < n) deg[i] = rsqrtf(deg[i] + 1.0f);  // +1 = self loop; always > 0
}

// ---------------- dense GEMM: T[n x 64] = X[n x DIN] @ W[DIN x 64] ----------------
template <int DIN>
__global__ __launch_bounds__(256) void gemm_kernel(const float* __restrict__ X,
                                                   const float* __restrict__ W,
                                                   float* __restrict__ T, int n) {
    // block tile: 64 nodes x 64 cols; K staged in chunks of 32
    __shared__ float xs[64][33];   // +1 pad: avoids bank conflict on column reads
    __shared__ float ws[32][64];
    const int t  = threadIdx.x;
    const int n0 = blockIdx.x * 64;
    const int tc = t & 15;   // channel group -> cols tc*4..tc*4+3
    const int tr = t >> 4;   // node group   -> rows tr*4..tr*4+3

    float acc[4][4] = {};

    for (int k0 = 0; k0 < DIN; k0 += 32) {
        // stage 64x32 X tile (512 float4 loads, coalesced)
        for (int l = t; l < 512; l += 256) {
            int r = l >> 3;          // [0,64)
            int q = (l & 7) << 2;    // [0,32) step 4
            int row = n0 + r;
            float4 v = make_float4(0.f, 0.f, 0.f, 0.f);
            if (row < n) v = *reinterpret_cast<const float4*>(&X[(long)row * DIN + k0 + q]);
            xs[r][q + 0] = v.x; xs[r][q + 1] = v.y; xs[r][q + 2] = v.z; xs[r][q + 3] = v.w;
        }
        // stage 32x64 W tile (512 float4 loads)
        for (int l = t; l < 512; l += 256) {
            int r = l >> 4;          // [0,32)  -- FIXED (was l>>3: OOB + wrong elements)
            int q = (l & 15) << 2;   // [0,64) step 4
            float4 v = *reinterpret_cast<const float4*>(&W[(long)(k0 + r) * 64 + q]);
            *reinterpret_cast<float4*>(&ws[r][q]) = v;
        }
        __syncthreads();
#pragma unroll
        for (int k = 0; k < 32; ++k) {
            float4 wv = *reinterpret_cast<const float4*>(&ws[k][tc * 4]);
#pragma unroll
            for (int j = 0; j < 4; ++j) {
                float xv = xs[tr * 4 + j][k];
                acc[j][0] += xv * wv.x;
                acc[j][1] += xv * wv.y;
                acc[j][2] += xv * wv.z;
                acc[j][3] += xv * wv.w;
            }
        }
        __syncthreads();
    }

    for (int j = 0; j < 4; ++j) {
        int row = n0 + tr * 4 + j;
        if (row < n) {
            *reinterpret_cast<float4*>(&T[(long)row * 64 + tc * 4]) =
                make_float4(acc[j][0], acc[j][1], acc[j][2], acc[j][3]);
        }
    }
}

// ---------------- edge scatter: agg[dst] += T[src] * dinv[src]*dinv[dst] ----------------
__global__ __launch_bounds__(256) void scatter_kernel(const float* __restrict__ T,
                                                      const int* __restrict__ src,
                                                      const int* __restrict__ dst,
                                                      const float* __restrict__ dinv,
                                                      float* __restrict__ agg, int E) {
    long tid = (long)blockIdx.x * blockDim.x + threadIdx.x;
    long stride = (long)gridDim.x * blockDim.x;
    long total = (long)E * 16;  // 16 threads per edge, 4 channels each
    for (; tid < total; tid += stride) {
        int e = (int)(tid >> 4);
        int q = (int)(tid & 15) << 2;
        int s = src[e];
        int d = dst[e];
        float norm = dinv[s] * dinv[d];
        float4 v = *reinterpret_cast<const float4*>(&T[(long)s * 64 + q]);
        float* o = &agg[(long)d * 64 + q];
        atomicAdd(o + 0, v.x * norm);
        atomicAdd(o + 1, v.y * norm);
        atomicAdd(o + 2, v.z * norm);
        atomicAdd(o + 3, v.w * norm);
    }
}

// ---------------- finalize: self-loop + bias + ReLU + LayerNorm (one wave per node) ----------------
__global__ __launch_bounds__(256) void finalize_ln_kernel(const float* __restrict__ agg,
                                                          const float* __restrict__ T,
                                                          const float* __restrict__ dinv,
                                                          const float* __restrict__ b,
                                                          const float* __restrict__ g,
                                                          const float* __restrict__ beta,
                                                          float* __restrict__ H, int n) {
    int lane = threadIdx.x & 63;
    int node = blockIdx.x * 4 + (threadIdx.x >> 6);
    if (node >= n) return;
    float di = dinv[node];
    float sc = di * di;
    long idx = (long)node * 64 + lane;
    float v = agg[idx] + T[idx] * sc + b[lane];
    v = fmaxf(v, 0.0f);  // ReLU
    // LayerNorm across the 64 channels (= the 64 lanes)
    float s = v;
#pragma unroll
    for (int off = 32; off > 0; off >>= 1) s += __shfl_xor(s, off, 64);
    float mu = s * (1.0f / 64.0f);
    float d = v - mu;
    float qq = d * d;
#pragma unroll
    for (int off = 32; off > 0; off >>= 1) qq += __shfl_xor(qq, off, 64);
    float var = qq * (1.0f / 64.0f);
    H[idx] = d * rsqrtf(var + LN_EPS) * g[lane] + beta[lane];
}

// ---------------- last layer: self-loop + bias, straight to output ----------------
__global__ __launch_bounds__(256) void final_out_kernel(const float* __restrict__ agg,
                                                        const float* __restrict__ T,
                                                        const float* __restrict__ dinv,
                                                        const float* __restrict__ b,
                                                        float* __restrict__ out, int n) {
    int i = blockIdx.x * blockDim.x + threadIdx.x;
    int stride = gridDim.x * blockDim.x;
    int total = n * 16;
    for (; i < total; i += stride) {
        int node = i >> 4;
        int q = (i & 15) << 2;
        float di = dinv[node];
        float sc = di * di;
        float4 a = *reinterpret_cast<const float4*>(&agg[(long)node * 64 + q]);
        float4 tv = *reinterpret_cast<const float4*>(&T[(long)node * 64 + q]);
        float4 r;
        r.x = a.x + tv.x * sc + b[q + 0];
        r.y = a.y + tv.y * sc + b[q + 1];
        r.z = a.z + tv.z * sc + b[q + 2];
        r.w = a.w + tv.w * sc + b[q + 3];
        *reinterpret_cast<float4*>(&out[(long)node * 64 + q]) = r;
    }
}

extern "C" void kernel_launch(void* const* d_in, const int* in_sizes, int n_in,
                              void* d_out, int out_size, void* d_ws, size_t ws_size,
                              hipStream_t stream) {
    const float* x    = (const float*)d_in[0];
    const int*   ei   = (const int*)d_in[1];
    const float* W_in = (const float*)d_in[2];
    const float* b_in = (const float*)d_in[3];
    const float* g_in = (const float*)d_in[4];
    const float* be_in= (const float*)d_in[5];
    const float* W_h  = (const float*)d_in[6];
    const float* b_h  = (const float*)d_in[7];
    const float* g_h  = (const float*)d_in[8];
    const float* be_h = (const float*)d_in[9];
    const float* W_out= (const float*)d_in[10];
    const float* b_out= (const float*)d_in[11];
    float* out = (float*)d_out;

    const int n = in_sizes[0] / 128;   // 100000
    const int E = in_sizes[1] / 2;     // 1600000
    const int* src = ei;
    const int* dst = ei + E;

    // workspace layout (fp32): dinv[NP] | T[NP*64] | agg[NP*64] | H[NP*64]
    const long NP = ((long)n + 127) & ~127L;
    float* dinv = (float*)d_ws;
    float* T    = dinv + NP;
    float* agg  = T + NP * 64;
    float* H    = agg + NP * 64;

    const size_t agg_bytes = (size_t)n * 64 * sizeof(float);

    // degree^{-1/2} (shared by all 3 layers: same dst list)
    hipMemsetAsync(dinv, 0, (size_t)n * sizeof(float), stream);
    deg_kernel<<<2048, 256, 0, stream>>>(dst, E, dinv);
    dinv_kernel<<<(n + 255) / 256, 256, 0, stream>>>(dinv, n);

    // ---- layer 1: x[100000x128] ----
    gemm_kernel<128><<<(n + 63) / 64, 256, 0, stream>>>(x, W_in, T, n);
    hipMemsetAsync(agg, 0, agg_bytes, stream);
    scatter_kernel<<<4096, 256, 0, stream>>>(T, src, dst, dinv, agg, E);
    finalize_ln_kernel<<<(n + 3) / 4, 256, 0, stream>>>(agg, T, dinv, b_in, g_in, be_in, H, n);

    // ---- layer 2 ----
    gemm_kernel<64><<<(n + 63) / 64, 256, 0, stream>>>(H, W_h, T, n);
    hipMemsetAsync(agg, 0, agg_bytes, stream);
    scatter_kernel<<<4096, 256, 0, stream>>>(T, src, dst, dinv, agg, E);
    finalize_ln_kernel<<<(n + 3) / 4, 256, 0, stream>>>(agg, T, dinv, b_h, g_h, be_h, H, n);

    // ---- layer 3 (no ReLU/LN) ----
    gemm_kernel<64><<<(n + 63) / 64, 256, 0, stream>>>(H, W_out, T, n);
    hipMemsetAsync(agg, 0, agg_bytes, stream);
    scatter_kernel<<<4096, 256, 0, stream>>>(T, src, dst, dinv, agg, E);
    final_out_kernel<<<4096, 256, 0, stream>>>(agg, T, dinv, b_out, out, n);
}

// Round 3
// 420.639 us; speedup vs baseline: 10.2227x; 10.2227x over previous
//
#include <hip/hip_runtime.h>

// GraphEncoder: 3x (GCNConv -> [ReLU -> LayerNorm]) on N=100000 nodes, E=1.6M edges.
// All fp32. Layer dims: 128->64, 64->64, 64->64.
// Round 3: scatter(atomics, 75G atomics/s ceiling) -> CSR-transpose + gather (no fp32 atomics).

constexpr float LN_EPS = 1e-5f;

// ---------------- int degree histogram ----------------
__global__ void deg_kernel(const int* __restrict__ dst, int E, int* __restrict__ deg) {
    int i = blockIdx.x * blockDim.x + threadIdx.x;
    int stride = gridDim.x * blockDim.x;
    for (; i < E; i += stride) atomicAdd(&deg[dst[i]], 1);
}

__global__ void dinv_kernel(const int* __restrict__ deg, float* __restrict__ dinv, int n) {
    int i = blockIdx.x * blockDim.x + threadIdx.x;
    if (i < n) dinv[i] = rsqrtf((float)deg[i] + 1.0f);  // +1 = self loop
}

// ---------------- exclusive scan of deg -> starts (3 kernels) ----------------
// Kernel A: per-block (1024 elems) exclusive scan + block totals
__global__ __launch_bounds__(256) void scan_block_kernel(const int* __restrict__ deg, int n,
                                                         int* __restrict__ starts,
                                                         int* __restrict__ bsum) {
    __shared__ int wsum[4];
    const int b = blockIdx.x, t = threadIdx.x;
    const int lane = t & 63, w = t >> 6;
    const int base = b * 1024 + t * 4;
    int v0 = (base + 0 < n) ? deg[base + 0] : 0;
    int v1 = (base + 1 < n) ? deg[base + 1] : 0;
    int v2 = (base + 2 < n) ? deg[base + 2] : 0;
    int v3 = (base + 3 < n) ? deg[base + 3] : 0;
    int s = v0 + v1 + v2 + v3;
    int inc = s;
#pragma unroll
    for (int off = 1; off < 64; off <<= 1) {
        int u = __shfl_up(inc, off, 64);
        if (lane >= off) inc += u;
    }
    if (lane == 63) wsum[w] = inc;
    __syncthreads();
    int woff = 0;
#pragma unroll
    for (int i = 0; i < 4; ++i)
        if (i < w) woff += wsum[i];
    int ex = woff + inc - s;  // exclusive prefix of this thread's 4-chunk
    if (base + 0 < n) starts[base + 0] = ex;
    if (base + 1 < n) starts[base + 1] = ex + v0;
    if (base + 2 < n) starts[base + 2] = ex + v0 + v1;
    if (base + 3 < n) starts[base + 3] = ex + v0 + v1 + v2;
    if (t == 255) bsum[b] = woff + inc;
}

// Kernel B: exclusive scan of block totals (nb <= 128), single block of 128
__global__ void scan_bsum_kernel(int* __restrict__ bsum, int nb) {
    __shared__ int w0sum;
    const int t = threadIdx.x, lane = t & 63, w = t >> 6;
    int v = (t < nb) ? bsum[t] : 0;
    int inc = v;
#pragma unroll
    for (int off = 1; off < 64; off <<= 1) {
        int u = __shfl_up(inc, off, 64);
        if (lane >= off) inc += u;
    }
    if (w == 0 && lane == 63) w0sum = inc;
    __syncthreads();
    int ex = inc - v + ((w == 1) ? w0sum : 0);
    if (t < nb) bsum[t] = ex;
}

// Kernel C: add block offsets; duplicate into cursor for bucket-fill
__global__ __launch_bounds__(256) void add_off_kernel(int* __restrict__ starts,
                                                      const int* __restrict__ bsum,
                                                      int* __restrict__ cursor, int n) {
    const int off = bsum[blockIdx.x];
    const int base = blockIdx.x * 1024 + threadIdx.x * 4;
#pragma unroll
    for (int j = 0; j < 4; ++j) {
        int idx = base + j;
        if (idx < n) {
            int val = starts[idx] + off;
            starts[idx] = val;
            cursor[idx] = val;
        }
    }
}

// ---------------- bucket fill: eidx[pos] = (src, norm) grouped by dst ----------------
__global__ __launch_bounds__(256) void fill_kernel(const int* __restrict__ src,
                                                   const int* __restrict__ dst,
                                                   const float* __restrict__ dinv,
                                                   int* __restrict__ cursor,
                                                   int2* __restrict__ eidx, int E) {
    int i = blockIdx.x * blockDim.x + threadIdx.x;
    int stride = gridDim.x * blockDim.x;
    for (; i < E; i += stride) {
        int s = src[i], d = dst[i];
        float norm = dinv[s] * dinv[d];
        int pos = atomicAdd(&cursor[d], 1);
        eidx[pos] = make_int2(s, __float_as_int(norm));
    }
}

// ---------------- dense GEMM: T[n x 64] = X[n x DIN] @ W[DIN x 64] ----------------
template <int DIN>
__global__ __launch_bounds__(256) void gemm_kernel(const float* __restrict__ X,
                                                   const float* __restrict__ W,
                                                   float* __restrict__ T, int n) {
    __shared__ float xs[64][33];
    __shared__ float ws[32][64];
    const int t  = threadIdx.x;
    const int n0 = blockIdx.x * 64;
    const int tc = t & 15;
    const int tr = t >> 4;

    float acc[4][4] = {};

    for (int k0 = 0; k0 < DIN; k0 += 32) {
        for (int l = t; l < 512; l += 256) {
            int r = l >> 3;
            int q = (l & 7) << 2;
            int row = n0 + r;
            float4 v = make_float4(0.f, 0.f, 0.f, 0.f);
            if (row < n) v = *reinterpret_cast<const float4*>(&X[(long)row * DIN + k0 + q]);
            xs[r][q + 0] = v.x; xs[r][q + 1] = v.y; xs[r][q + 2] = v.z; xs[r][q + 3] = v.w;
        }
        for (int l = t; l < 512; l += 256) {
            int r = l >> 4;
            int q = (l & 15) << 2;
            float4 v = *reinterpret_cast<const float4*>(&W[(long)(k0 + r) * 64 + q]);
            *reinterpret_cast<float4*>(&ws[r][q]) = v;
        }
        __syncthreads();
#pragma unroll
        for (int k = 0; k < 32; ++k) {
            float4 wv = *reinterpret_cast<const float4*>(&ws[k][tc * 4]);
#pragma unroll
            for (int j = 0; j < 4; ++j) {
                float xv = xs[tr * 4 + j][k];
                acc[j][0] += xv * wv.x;
                acc[j][1] += xv * wv.y;
                acc[j][2] += xv * wv.z;
                acc[j][3] += xv * wv.w;
            }
        }
        __syncthreads();
    }

    for (int j = 0; j < 4; ++j) {
        int row = n0 + tr * 4 + j;
        if (row < n) {
            *reinterpret_cast<float4*>(&T[(long)row * 64 + tc * 4]) =
                make_float4(acc[j][0], acc[j][1], acc[j][2], acc[j][3]);
        }
    }
}

// ---------------- fused gather + self-loop + bias (+ ReLU + LayerNorm) ----------------
// One wave per node; lane = channel. MODE 0: ReLU+LN -> H.  MODE 1: plain -> out.
template <int MODE>
__global__ __launch_bounds__(256) void gather_kernel(const float* __restrict__ T,
                                                     const int* __restrict__ starts,
                                                     const int2* __restrict__ eidx,
                                                     const float* __restrict__ dinv,
                                                     const float* __restrict__ b,
                                                     const float* __restrict__ g,
                                                     const float* __restrict__ beta,
                                                     float* __restrict__ out, int n, int E) {
    const int lane = threadIdx.x & 63;
    const int node = blockIdx.x * 4 + (threadIdx.x >> 6);
    if (node >= n) return;
    int beg = starts[node];
    int end = (node == n - 1) ? E : starts[node + 1];
    beg = __builtin_amdgcn_readfirstlane(beg);
    end = __builtin_amdgcn_readfirstlane(end);

    float acc = 0.0f;
    int k = beg;
    for (; k + 4 <= end; k += 4) {
        int2 p0 = eidx[k + 0];
        int2 p1 = eidx[k + 1];
        int2 p2 = eidx[k + 2];
        int2 p3 = eidx[k + 3];
        float v0 = T[(long)p0.x * 64 + lane];
        float v1 = T[(long)p1.x * 64 + lane];
        float v2 = T[(long)p2.x * 64 + lane];
        float v3 = T[(long)p3.x * 64 + lane];
        acc += v0 * __int_as_float(p0.y);
        acc += v1 * __int_as_float(p1.y);
        acc += v2 * __int_as_float(p2.y);
        acc += v3 * __int_as_float(p3.y);
    }
    for (; k < end; ++k) {
        int2 p = eidx[k];
        acc += T[(long)p.x * 64 + lane] * __int_as_float(p.y);
    }

    const float di = dinv[node];
    const long idx = (long)node * 64 + lane;
    float v = acc + T[idx] * di * di + b[lane];

    if (MODE == 0) {
        v = fmaxf(v, 0.0f);
        float s = v;
#pragma unroll
        for (int off = 32; off > 0; off >>= 1) s += __shfl_xor(s, off, 64);
        float mu = s * (1.0f / 64.0f);
        float d = v - mu;
        float qq = d * d;
#pragma unroll
        for (int off = 32; off > 0; off >>= 1) qq += __shfl_xor(qq, off, 64);
        float var = qq * (1.0f / 64.0f);
        out[idx] = d * rsqrtf(var + LN_EPS) * g[lane] + beta[lane];
    } else {
        out[idx] = v;
    }
}

extern "C" void kernel_launch(void* const* d_in, const int* in_sizes, int n_in,
                              void* d_out, int out_size, void* d_ws, size_t ws_size,
                              hipStream_t stream) {
    const float* x    = (const float*)d_in[0];
    const int*   ei   = (const int*)d_in[1];
    const float* W_in = (const float*)d_in[2];
    const float* b_in = (const float*)d_in[3];
    const float* g_in = (const float*)d_in[4];
    const float* be_in= (const float*)d_in[5];
    const float* W_h  = (const float*)d_in[6];
    const float* b_h  = (const float*)d_in[7];
    const float* g_h  = (const float*)d_in[8];
    const float* be_h = (const float*)d_in[9];
    const float* W_out= (const float*)d_in[10];
    const float* b_out= (const float*)d_in[11];
    float* out = (float*)d_out;

    const int n = in_sizes[0] / 128;   // 100000
    const int E = in_sizes[1] / 2;     // 1600000
    const int* src = ei;
    const int* dst = ei + E;

    // workspace layout: eidx[E int2] | dinv[NP f] | degi[NP i] | starts[NP i] | cursor[NP i] | bsum[1024 i] | T[NP*64 f] | H[NP*64 f]
    const long NP = ((long)n + 127) & ~127L;
    int2*  eidx   = (int2*)d_ws;
    float* dinv   = (float*)(eidx + E);
    int*   degi   = (int*)(dinv + NP);
    int*   starts = degi + NP;
    int*   cursor = starts + NP;
    int*   bsum   = cursor + NP;
    float* T      = (float*)(bsum + 1024);
    float* H      = T + NP * 64;

    const int nb = (n + 1023) / 1024;  // 98 blocks for the scan (<=128 required)

    // ---- CSR-transpose build (once; shared by all 3 layers) ----
    hipMemsetAsync(degi, 0, (size_t)n * sizeof(int), stream);
    deg_kernel<<<2048, 256, 0, stream>>>(dst, E, degi);
    dinv_kernel<<<(n + 255) / 256, 256, 0, stream>>>(degi, dinv, n);
    scan_block_kernel<<<nb, 256, 0, stream>>>(degi, n, starts, bsum);
    scan_bsum_kernel<<<1, 128, 0, stream>>>(bsum, nb);
    add_off_kernel<<<nb, 256, 0, stream>>>(starts, bsum, cursor, n);
    fill_kernel<<<2048, 256, 0, stream>>>(src, dst, dinv, cursor, eidx, E);

    const int ggrid = (n + 3) / 4;

    // ---- layer 1: x[100000x128] ----
    gemm_kernel<128><<<(n + 63) / 64, 256, 0, stream>>>(x, W_in, T, n);
    gather_kernel<0><<<ggrid, 256, 0, stream>>>(T, starts, eidx, dinv, b_in, g_in, be_in, H, n, E);

    // ---- layer 2 ----
    gemm_kernel<64><<<(n + 63) / 64, 256, 0, stream>>>(H, W_h, T, n);
    gather_kernel<0><<<ggrid, 256, 0, stream>>>(T, starts, eidx, dinv, b_h, g_h, be_h, H, n, E);

    // ---- layer 3 (no ReLU/LN, straight to output) ----
    gemm_kernel<64><<<(n + 63) / 64, 256, 0, stream>>>(H, W_out, T, n);
    gather_kernel<1><<<ggrid, 256, 0, stream>>>(T, starts, eidx, dinv, b_out, nullptr, nullptr, out, n, E);
}